// Round 5
// baseline (163.310 us; speedup 1.0000x reference)
//
#include <hip/hip_runtime.h>
#include <hip/hip_bf16.h>
#include <stdint.h>

#define NT 20000
#define DIM 1024
#define HID 512
#define DATT_N 256
#define NCLUS 10
#define NCLS_N 4
#define NRT 157       // ceil(NT/128)
#define NBS 79        // ceil(NT/256) sort blocks

typedef __bf16 bf16;
typedef __attribute__((ext_vector_type(8))) __bf16 bf16x8;
typedef __attribute__((ext_vector_type(4))) float f32x4;

__device__ __forceinline__ void gload_lds16(const void* g, void* l) {
  __builtin_amdgcn_global_load_lds(
      (const __attribute__((address_space(1))) unsigned int*)g,
      (__attribute__((address_space(3))) unsigned int*)l, 16, 0, 0);
}

// ---------------- deterministic cluster sort (no global atomics) ----------------

__global__ void zero_pool(float* pool) {
  int i = blockIdx.x * 256 + threadIdx.x;
  if (i < NCLUS * HID) pool[i] = 0.f;
}

// per-block cluster histogram via wave ballots
__global__ __launch_bounds__(256) void hist_kernel(const int* __restrict__ cid,
                                                   int* __restrict__ blkcnt) {
  __shared__ int wcnt[4][16];
  int tid = threadIdx.x;
  int lane = tid & 63, w = tid >> 6;
  int n = blockIdx.x * 256 + tid;
  int mycid = (n < NT) ? cid[n] : -1;
#pragma unroll
  for (int c = 0; c < NCLUS; ++c) {
    unsigned long long m = __ballot(mycid == c);
    if (lane == c) wcnt[w][c] = __popcll(m);
  }
  __syncthreads();
  if (tid < NCLUS)
    blkcnt[blockIdx.x * NCLUS + tid] =
        wcnt[0][tid] + wcnt[1][tid] + wcnt[2][tid] + wcnt[3][tid];
}

// per-cluster scan over blocks -> blkbase, cnt, offs
__global__ void prefix_kernel(const int* __restrict__ blkcnt, int* __restrict__ blkbase,
                              int* __restrict__ cnt, int* __restrict__ offs) {
  int c = threadIdx.x;
  if (c < NCLUS) {
    int run = 0;
    for (int b = 0; b < NBS; ++b) {
      blkbase[b * NCLUS + c] = run;
      run += blkcnt[b * NCLUS + c];
    }
    cnt[c] = run;
  }
  __syncthreads();
  if (c == 0) {
    int a = 0;
    for (int i = 0; i < NCLUS; ++i) { offs[i] = a; a += cnt[i]; }
    offs[NCLUS] = a;
  }
}

// order[offs[c] + blkbase + waveprefix + rank_in_wave] = n
__global__ __launch_bounds__(256) void scatter2_kernel(
    const int* __restrict__ cid, const int* __restrict__ blkbase,
    const int* __restrict__ offs, int* __restrict__ order) {
  __shared__ int wcnt[4][16];
  __shared__ int wbase[4][16];
  int tid = threadIdx.x;
  int lane = tid & 63, w = tid >> 6;
  int n = blockIdx.x * 256 + tid;
  int mycid = (n < NT) ? cid[n] : -1;
  unsigned long long lmask = (lane == 63) ? ~0ull >> 1 : (1ull << lane) - 1;
  int myrank = 0;
#pragma unroll
  for (int c = 0; c < NCLUS; ++c) {
    unsigned long long m = __ballot(mycid == c);
    if (mycid == c) myrank = __popcll(m & lmask);
    if (lane == c) wcnt[w][c] = __popcll(m);
  }
  __syncthreads();
  if (tid < NCLUS) {
    int pre = blkbase[blockIdx.x * NCLUS + tid];
#pragma unroll
    for (int ww = 0; ww < 4; ++ww) { wbase[ww][tid] = pre; pre += wcnt[ww][tid]; }
  }
  __syncthreads();
  if (n < NT) order[offs[mycid] + wbase[w][mycid] + myrank] = n;
}

// xs[i][:] = bf16(x[order[i]][:])  -- sorted, casted copy of x
__global__ void gather_cast(const float* __restrict__ x, const int* __restrict__ order,
                            bf16* __restrict__ xs) {
  int t = blockIdx.x * 256 + threadIdx.x;  // one thread per 8 elements
  int row = t >> 7;                        // 128 threads per row (1024 elems)
  if (row >= NT) return;
  int col = (t & 127) << 3;
  const f32x4* p = (const f32x4*)(x + (size_t)order[row] * DIM + col);
  f32x4 u = p[0], v = p[1];
  bf16x8 w;
  w[0] = (bf16)u[0]; w[1] = (bf16)u[1]; w[2] = (bf16)u[2]; w[3] = (bf16)u[3];
  w[4] = (bf16)v[0]; w[5] = (bf16)v[1]; w[6] = (bf16)v[2]; w[7] = (bf16)v[3];
  *(bf16x8*)(xs + (size_t)row * DIM + col) = w;
}

// dst[b][j][i] = bf16(src[b][i][j]) ; src is R x Cc per batch b
__global__ void transpose_cast(const float* __restrict__ src, bf16* __restrict__ dst,
                               int R, int Cc) {
  __shared__ float t[32][33];
  int b = blockIdx.z;
  int i0 = blockIdx.y * 32, j0 = blockIdx.x * 32;
  const float* s = src + (size_t)b * R * Cc;
  bf16* d = dst + (size_t)b * R * Cc;
  int tx = threadIdx.x & 31, ty = threadIdx.x >> 5;
#pragma unroll
  for (int yy = 0; yy < 32; yy += 8)
    t[ty + yy][tx] = s[(size_t)(i0 + ty + yy) * Cc + (j0 + tx)];
  __syncthreads();
#pragma unroll
  for (int yy = 0; yy < 32; yy += 8)
    d[(size_t)(j0 + ty + yy) * R + (i0 + tx)] = (bf16)t[tx][ty + yy];
}

// XCD-grouping decode: the 4 n-blocks of one (cluster,row-tile) group get
// dispatch slots congruent mod 8 -> same XCD L2 serves the shared A panel.
__device__ __forceinline__ bool decode_grp(int d, int& c, int& rt, int& j) {
  int x8 = d & 7, s = d >> 3;
  int g = (s >> 2) * 8 + x8;
  if (g >= NRT * NCLUS) return false;
  j = s & 3;
  c = g / NRT;
  rt = g - c * NRT;
  return true;
}

// ---------------- GEMM1: h1 = relu(xs @ W1[c]^T + b1[c]) ----------------
// T3-minimum 2-phase: double-buffered LDS, one barrier per K-step, next-tile
// global_load_lds issued after frag ds_reads so HBM latency hides under MFMA.

__global__ __launch_bounds__(256, 2) void gemm1_kernel(
    const bf16* __restrict__ xs, const bf16* __restrict__ w1t, const float* __restrict__ b1,
    const int* __restrict__ offs, const int* __restrict__ cnt, bf16* __restrict__ h1) {
  int c, rt, j;
  if (!decode_grp(blockIdx.x, c, rt, j)) return;
  int cntc = cnt[c];
  int row0 = rt * 128;
  if (row0 >= cntc) return;
  int seg = offs[c];
  int n0 = j * 128;

  __shared__ bf16 Als[2][128 * 64];  // [row][k]
  __shared__ bf16 Bls[2][128 * 64];  // [n][k]

  int tid = threadIdx.x;
  int lane = tid & 63, wid = tid >> 6;
  int wr = wid >> 1, wc = wid & 1;

  const bf16* aptr[4]; int aoff[4];
  const bf16* bptr[4]; int boff[4];
#pragma unroll
  for (int i = 0; i < 4; ++i) {
    int chunk = i * 4 + wid;              // 0..15, 512 bf16 per wave-chunk
    int r = chunk * 8 + (lane >> 3);      // tile row 0..127
    int kk = (lane & 7) << 3;
    int ar = seg + row0 + r; if (ar > NT - 1) ar = NT - 1;
    aptr[i] = xs + (size_t)ar * DIM + kk;
    aoff[i] = chunk * 512;
    bptr[i] = w1t + (size_t)(c * HID + n0 + r) * DIM + kk;
    boff[i] = chunk * 512;
  }

  f32x4 acc[4][4];
#pragma unroll
  for (int m = 0; m < 4; m++)
#pragma unroll
    for (int n = 0; n < 4; n++) acc[m][n] = {0.f, 0.f, 0.f, 0.f};

  // prologue: stage tile 0 into buffer 0
#pragma unroll
  for (int i = 0; i < 4; ++i) gload_lds16(aptr[i], &Als[0][aoff[i]]);
#pragma unroll
  for (int i = 0; i < 4; ++i) gload_lds16(bptr[i], &Bls[0][boff[i]]);

  const int NKT = DIM / 64;
#pragma unroll 2
  for (int t = 0; t < NKT; ++t) {
    __syncthreads();  // drains vmcnt(0): buf[t&1] staged; prior reads of buf[(t+1)&1] done
    const bf16* Ab = &Als[t & 1][0];
    const bf16* Bb = &Bls[t & 1][0];
    // read all fragments into registers first (so stage below overlaps MFMA)
    bf16x8 a[2][4], b[2][4];
#pragma unroll
    for (int ks = 0; ks < 2; ++ks) {
      int ko = ks * 32 + ((lane >> 4) << 3);
#pragma unroll
      for (int m = 0; m < 4; m++)
        a[ks][m] = *(const bf16x8*)(&Ab[(wr * 64 + m * 16 + (lane & 15)) * 64 + ko]);
#pragma unroll
      for (int n = 0; n < 4; n++)
        b[ks][n] = *(const bf16x8*)(&Bb[(wc * 64 + n * 16 + (lane & 15)) * 64 + ko]);
    }
    if (t + 1 < NKT) {
      int k0 = (t + 1) * 64;
      int nb = (t + 1) & 1;
#pragma unroll
      for (int i = 0; i < 4; ++i) gload_lds16(aptr[i] + k0, &Als[nb][aoff[i]]);
#pragma unroll
      for (int i = 0; i < 4; ++i) gload_lds16(bptr[i] + k0, &Bls[nb][boff[i]]);
    }
#pragma unroll
    for (int ks = 0; ks < 2; ++ks)
#pragma unroll
      for (int m = 0; m < 4; m++)
#pragma unroll
        for (int n = 0; n < 4; n++)
          acc[m][n] = __builtin_amdgcn_mfma_f32_16x16x32_bf16(a[ks][m], b[ks][n], acc[m][n], 0, 0, 0);
  }

  int valid = cntc - row0; if (valid > 128) valid = 128;
#pragma unroll
  for (int n = 0; n < 4; n++) {
    int col = n0 + wc * 64 + n * 16 + (lane & 15);
    float bias = b1[c * HID + col];
#pragma unroll
    for (int m = 0; m < 4; m++) {
      int rbase = wr * 64 + m * 16 + ((lane >> 4) << 2);
#pragma unroll
      for (int e = 0; e < 4; e++) {
        int r = rbase + e;
        if (r < valid) {
          float v = acc[m][n][e] + bias;
          h1[(size_t)(seg + row0 + r) * HID + col] = (bf16)(v > 0.f ? v : 0.f);
        }
      }
    }
  }
}

// ---------------- GEMM2: pool[c] += colsum(relu(h1 @ W2[c]^T + b2[c])) ----------------

__global__ __launch_bounds__(256, 2) void gemm2_kernel(
    const bf16* __restrict__ h1, const bf16* __restrict__ w2t, const float* __restrict__ b2,
    const int* __restrict__ offs, const int* __restrict__ cnt, float* __restrict__ pool) {
  int c, rt, j;
  if (!decode_grp(blockIdx.x, c, rt, j)) return;
  int cntc = cnt[c];
  int row0 = rt * 128;
  if (row0 >= cntc) return;
  int seg = offs[c];
  int n0 = j * 128;
  int valid = cntc - row0; if (valid > 128) valid = 128;

  __shared__ bf16 Als[2][128 * 64];
  __shared__ bf16 Bls[2][128 * 64];

  int tid = threadIdx.x;
  int lane = tid & 63, wid = tid >> 6;
  int wr = wid >> 1, wc = wid & 1;

  const bf16* aptr[4]; int aoff[4];
  const bf16* bptr[4]; int boff[4];
#pragma unroll
  for (int i = 0; i < 4; ++i) {
    int chunk = i * 4 + wid;
    int r = chunk * 8 + (lane >> 3);
    int kk = (lane & 7) << 3;
    int ar = seg + row0 + r; if (ar > NT - 1) ar = NT - 1;
    aptr[i] = h1 + (size_t)ar * HID + kk;
    aoff[i] = chunk * 512;
    bptr[i] = w2t + (size_t)(c * HID + n0 + r) * HID + kk;
    boff[i] = chunk * 512;
  }

  f32x4 acc[4][4];
#pragma unroll
  for (int m = 0; m < 4; m++)
#pragma unroll
    for (int n = 0; n < 4; n++) acc[m][n] = {0.f, 0.f, 0.f, 0.f};

  // prologue
#pragma unroll
  for (int i = 0; i < 4; ++i) gload_lds16(aptr[i], &Als[0][aoff[i]]);
#pragma unroll
  for (int i = 0; i < 4; ++i) gload_lds16(bptr[i], &Bls[0][boff[i]]);

  const int NKT = HID / 64;
#pragma unroll 2
  for (int t = 0; t < NKT; ++t) {
    __syncthreads();
    const bf16* Ab = &Als[t & 1][0];
    const bf16* Bb = &Bls[t & 1][0];
    bf16x8 a[2][4], b[2][4];
#pragma unroll
    for (int ks = 0; ks < 2; ++ks) {
      int ko = ks * 32 + ((lane >> 4) << 3);
#pragma unroll
      for (int m = 0; m < 4; m++)
        a[ks][m] = *(const bf16x8*)(&Ab[(wr * 64 + m * 16 + (lane & 15)) * 64 + ko]);
#pragma unroll
      for (int n = 0; n < 4; n++)
        b[ks][n] = *(const bf16x8*)(&Bb[(wc * 64 + n * 16 + (lane & 15)) * 64 + ko]);
    }
    if (t + 1 < NKT) {
      int k0 = (t + 1) * 64;
      int nb = (t + 1) & 1;
#pragma unroll
      for (int i = 0; i < 4; ++i) gload_lds16(aptr[i] + k0, &Als[nb][aoff[i]]);
#pragma unroll
      for (int i = 0; i < 4; ++i) gload_lds16(bptr[i] + k0, &Bls[nb][boff[i]]);
    }
#pragma unroll
    for (int ks = 0; ks < 2; ++ks)
#pragma unroll
      for (int m = 0; m < 4; m++)
#pragma unroll
        for (int n = 0; n < 4; n++)
          acc[m][n] = __builtin_amdgcn_mfma_f32_16x16x32_bf16(a[ks][m], b[ks][n], acc[m][n], 0, 0, 0);
  }

  // bias + relu + masked column-sum into pool
#pragma unroll
  for (int n = 0; n < 4; n++) {
    int col = n0 + wc * 64 + n * 16 + (lane & 15);
    float bias = b2[c * HID + col];
    float s = 0.f;
#pragma unroll
    for (int m = 0; m < 4; m++) {
      int rbase = wr * 64 + m * 16 + ((lane >> 4) << 2);
#pragma unroll
      for (int e = 0; e < 4; e++) {
        if (rbase + e < valid) {
          float v = acc[m][n][e] + bias;
          s += (v > 0.f ? v : 0.f);
        }
      }
    }
    s += __shfl_xor(s, 16);
    s += __shfl_xor(s, 32);
    if (lane < 16) atomicAdd(&pool[c * HID + n0 + wc * 64 + n * 16 + lane], s);
  }
}

// ---------------- tails (fp32, parallelized) ----------------

__global__ __launch_bounds__(256) void tail_fc(
    const float* __restrict__ pool, const int* __restrict__ cnt,
    const float* __restrict__ fcW, const float* __restrict__ fcb,
    float* __restrict__ hbuf) {
  int c = blockIdx.x >> 3;
  int jt = blockIdx.x & 7;
  __shared__ float hc[HID];
  __shared__ float red[4][64];
  int tid = threadIdx.x;
  float inv = 1.f / fmaxf((float)cnt[c], 1.f);
  for (int k = tid; k < HID; k += 256) hc[k] = pool[c * HID + k] * inv;
  __syncthreads();
  int jl = tid & 63, kg = tid >> 6;
  int j = jt * 64 + jl;
  float s = 0.f;
#pragma unroll 4
  for (int k = kg * 128; k < kg * 128 + 128; ++k) s += hc[k] * fcW[(size_t)k * HID + j];
  red[kg][jl] = s;
  __syncthreads();
  if (kg == 0) {
    float v = red[0][jl] + red[1][jl] + red[2][jl] + red[3][jl] + fcb[j];
    hbuf[c * HID + j] = fmaxf(v, 0.f);
  }
}

__global__ __launch_bounds__(1024) void tail_att(
    const float* __restrict__ hbuf,
    const float* __restrict__ Wa, const float* __restrict__ ba,
    const float* __restrict__ Wb, const float* __restrict__ bb,
    const float* __restrict__ Wc, const float* __restrict__ bc,
    float* __restrict__ score) {
  int c = blockIdx.x;
  __shared__ float h[HID];
  __shared__ float ra[4][DATT_N];
  __shared__ float rb[4][DATT_N];
  __shared__ float sc[DATT_N];
  int tid = threadIdx.x;
  for (int k = tid; k < HID; k += 1024) h[k] = hbuf[c * HID + k];
  __syncthreads();
  int jl = tid & 255, kg = tid >> 8;
  float sa = 0.f, sb = 0.f;
#pragma unroll 4
  for (int k = kg * 128; k < kg * 128 + 128; ++k) {
    float hv = h[k];
    sa += hv * Wa[(size_t)k * DATT_N + jl];
    sb += hv * Wb[(size_t)k * DATT_N + jl];
  }
  ra[kg][jl] = sa;
  rb[kg][jl] = sb;
  __syncthreads();
  if (kg == 0) {
    float va = ra[0][jl] + ra[1][jl] + ra[2][jl] + ra[3][jl] + ba[jl];
    float vb = rb[0][jl] + rb[1][jl] + rb[2][jl] + rb[3][jl] + bb[jl];
    float av = tanhf(va);
    float bv = 1.f / (1.f + expf(-vb));
    sc[jl] = av * bv * Wc[jl];
  }
  __syncthreads();
  for (int s2 = 128; s2 > 0; s2 >>= 1) {
    if (tid < s2) sc[tid] += sc[tid + s2];
    __syncthreads();
  }
  if (tid == 0) score[c] = sc[0] + bc[0];
}

__global__ __launch_bounds__(1024) void tail_fin(
    const float* __restrict__ score, const float* __restrict__ hbuf,
    const float* __restrict__ rhoW, const float* __restrict__ rhob,
    const float* __restrict__ clsW, const float* __restrict__ clsb,
    float* __restrict__ out) {
  __shared__ float Asm[NCLUS];
  __shared__ float hp[HID];
  __shared__ float rr[4][DATT_N];
  __shared__ float hr[DATT_N];
  __shared__ float lg[NCLS_N];
  int tid = threadIdx.x;
  if (tid == 0) {
    float mx = -1e30f;
    for (int c = 0; c < NCLUS; c++) mx = fmaxf(mx, score[c]);
    float sum = 0.f, e[NCLUS];
    for (int c = 0; c < NCLUS; c++) { e[c] = expf(score[c] - mx); sum += e[c]; }
    for (int c = 0; c < NCLUS; c++) Asm[c] = e[c] / sum;
  }
  __syncthreads();
  if (tid < HID) {
    float s = 0.f;
#pragma unroll
    for (int c = 0; c < NCLUS; c++) s += Asm[c] * hbuf[c * HID + tid];
    hp[tid] = s;
  }
  __syncthreads();
  int jl = tid & 255, kg = tid >> 8;
  float s = 0.f;
#pragma unroll 4
  for (int k = kg * 128; k < kg * 128 + 128; ++k) s += hp[k] * rhoW[(size_t)k * DATT_N + jl];
  rr[kg][jl] = s;
  __syncthreads();
  if (kg == 0) hr[jl] = fmaxf(rr[0][jl] + rr[1][jl] + rr[2][jl] + rr[3][jl] + rhob[jl], 0.f);
  __syncthreads();
  if (tid < NCLS_N * 64) {
    int t = tid >> 6, l = tid & 63;
    float cs = 0.f;
    for (int j = l; j < DATT_N; j += 64) cs += hr[j] * clsW[j * NCLS_N + t];
#pragma unroll
    for (int w = 32; w > 0; w >>= 1) cs += __shfl_xor(cs, w);
    if (l == 0) lg[t] = cs + clsb[t];
  }
  __syncthreads();
  if (tid == 0) {
    float mx = lg[0];
    int am = 0;
    for (int t = 1; t < NCLS_N; t++) if (lg[t] > mx) { mx = lg[t]; am = t; }
    float sum = 0.f, e[NCLS_N];
    for (int t = 0; t < NCLS_N; t++) { e[t] = expf(lg[t] - mx); sum += e[t]; }
    for (int t = 0; t < NCLS_N; t++) {
      out[t] = lg[t];
      out[NCLS_N + t] = e[t] / sum;
    }
    out[2 * NCLS_N] = (float)am;
  }
}

// ---------------- launch ----------------

extern "C" void kernel_launch(void* const* d_in, const int* in_sizes, int n_in,
                              void* d_out, int out_size, void* d_ws, size_t ws_size,
                              hipStream_t stream) {
  const float* x    = (const float*)d_in[0];
  const int*   cid  = (const int*)d_in[1];
  const float* W1   = (const float*)d_in[2];
  const float* b1   = (const float*)d_in[3];
  const float* W2   = (const float*)d_in[4];
  const float* b2   = (const float*)d_in[5];
  const float* fcW  = (const float*)d_in[6];
  const float* fcb  = (const float*)d_in[7];
  const float* Wa   = (const float*)d_in[8];
  const float* ba   = (const float*)d_in[9];
  const float* Wb   = (const float*)d_in[10];
  const float* bb   = (const float*)d_in[11];
  const float* Wc   = (const float*)d_in[12];
  const float* bc   = (const float*)d_in[13];
  const float* rhoW = (const float*)d_in[14];
  const float* rhob = (const float*)d_in[15];
  const float* clsW = (const float*)d_in[16];
  const float* clsb = (const float*)d_in[17];
  float* out = (float*)d_out;

  char* ws = (char*)d_ws;
  int*   cnt     = (int*)(ws + 0);
  int*   offs    = (int*)(ws + 64);
  float* score   = (float*)(ws + 128);
  int*   blkcnt  = (int*)(ws + 256);                    // NBS*NCLUS = 790 ints
  int*   blkbase = (int*)(ws + 256 + 4096);
  int*   order   = (int*)(ws + 256 + 8192);             // NT ints
  float* pool    = (float*)(ws + 256 + 8192 + 80000);
  float* hbuf    = (float*)(ws + 256 + 8192 + 80000 + NCLUS * HID * 4);
  size_t o = 256 + 8192 + 80000 + 2ull * NCLUS * HID * 4;
  o = (o + 255) & ~(size_t)255;
  bf16* w1t = (bf16*)(ws + o); o += (size_t)NCLUS * HID * DIM * 2;
  bf16* w2t = (bf16*)(ws + o); o += (size_t)NCLUS * HID * HID * 2;
  bf16* h1  = (bf16*)(ws + o); o += (size_t)NT * HID * 2;
  bf16* xs  = (bf16*)(ws + o); o += (size_t)NT * DIM * 2;

  zero_pool<<<dim3((NCLUS * HID + 255) / 256), dim3(256), 0, stream>>>(pool);
  hist_kernel<<<dim3(NBS), dim3(256), 0, stream>>>(cid, blkcnt);
  prefix_kernel<<<dim3(1), dim3(64), 0, stream>>>(blkcnt, blkbase, cnt, offs);
  scatter2_kernel<<<dim3(NBS), dim3(256), 0, stream>>>(cid, blkbase, offs, order);
  gather_cast<<<dim3(NT * 128 / 256), dim3(256), 0, stream>>>(x, order, xs);
  transpose_cast<<<dim3(HID / 32, DIM / 32, NCLUS), dim3(256), 0, stream>>>(W1, w1t, DIM, HID);
  transpose_cast<<<dim3(HID / 32, HID / 32, NCLUS), dim3(256), 0, stream>>>(W2, w2t, HID, HID);

  int nblk = 8 * ((NRT * NCLUS + 7) / 8) * 4;
  gemm1_kernel<<<dim3(nblk), dim3(256), 0, stream>>>(xs, w1t, b1, offs, cnt, h1);
  gemm2_kernel<<<dim3(nblk), dim3(256), 0, stream>>>(h1, w2t, b2, offs, cnt, pool);

  tail_fc<<<dim3(NCLUS * 8), dim3(256), 0, stream>>>(pool, cnt, fcW, fcb, hbuf);
  tail_att<<<dim3(NCLUS), dim3(1024), 0, stream>>>(hbuf, Wa, ba, Wb, bb, Wc, bc, score);
  tail_fin<<<dim3(1), dim3(1024), 0, stream>>>(score, hbuf, rhoW, rhob, clsW, clsb, out);
}

// Round 6
// 147.347 us; speedup vs baseline: 1.1083x; 1.1083x over previous
//
#include <hip/hip_runtime.h>
#include <hip/hip_bf16.h>
#include <stdint.h>

#define NT 20000
#define DIM 1024
#define HID 512
#define DATT_N 256
#define NCLUS 10
#define NCLS_N 4
#define NBS 79        // ceil(NT/256) sort blocks
#define NRT2 313      // ceil(NT/64) row tiles

typedef __bf16 bf16;
typedef __attribute__((ext_vector_type(8))) __bf16 bf16x8;
typedef __attribute__((ext_vector_type(4))) float f32x4;

__device__ __forceinline__ void gload_lds16(const void* g, void* l) {
  __builtin_amdgcn_global_load_lds(
      (const __attribute__((address_space(1))) unsigned int*)g,
      (__attribute__((address_space(3))) unsigned int*)l, 16, 0, 0);
}

// ---------------- fused setup: hist + zero_pool + W1/W2 transpose-cast ----------------

__device__ __forceinline__ void transpose_body(const float* __restrict__ s,
                                               bf16* __restrict__ d, int R, int Cc,
                                               int i0, int j0, float (*t)[33]) {
  int tx = threadIdx.x & 31, ty = threadIdx.x >> 5;
#pragma unroll
  for (int yy = 0; yy < 32; yy += 8)
    t[ty + yy][tx] = s[(size_t)(i0 + ty + yy) * Cc + (j0 + tx)];
  __syncthreads();
#pragma unroll
  for (int yy = 0; yy < 32; yy += 8)
    d[(size_t)(j0 + ty + yy) * R + (i0 + tx)] = (bf16)t[tx][ty + yy];
}

#define ZPB ((NCLUS * HID + 255) / 256)     // 20 zero blocks
#define TW1B (16 * 32 * NCLUS)              // 5120 W1-transpose blocks
#define TW2B (16 * 16 * NCLUS)              // 2560 W2-transpose blocks

__global__ __launch_bounds__(256) void setup_kernel(
    const int* __restrict__ cid, int* __restrict__ blkcnt, float* __restrict__ pool,
    const float* __restrict__ W1, bf16* __restrict__ w1t,
    const float* __restrict__ W2, bf16* __restrict__ w2t) {
  __shared__ float t[32][33];
  __shared__ int wcnt[4][16];
  int b = blockIdx.x;
  int tid = threadIdx.x;
  if (b < NBS) {
    // per-block cluster histogram via wave ballots
    int lane = tid & 63, w = tid >> 6;
    int n = b * 256 + tid;
    int mycid = (n < NT) ? cid[n] : -1;
#pragma unroll
    for (int c = 0; c < NCLUS; ++c) {
      unsigned long long m = __ballot(mycid == c);
      if (lane == c) wcnt[w][c] = __popcll(m);
    }
    __syncthreads();
    if (tid < NCLUS)
      blkcnt[b * NCLUS + tid] =
          wcnt[0][tid] + wcnt[1][tid] + wcnt[2][tid] + wcnt[3][tid];
  } else if (b < NBS + ZPB) {
    int i = (b - NBS) * 256 + tid;
    if (i < NCLUS * HID) pool[i] = 0.f;
  } else if (b < NBS + ZPB + TW1B) {
    int bb = b - NBS - ZPB;            // z*512 + y*16 + x ; R=DIM, Cc=HID
    int z = bb >> 9, r = bb & 511, y = r >> 4, x = r & 15;
    transpose_body(W1 + (size_t)z * DIM * HID, w1t + (size_t)z * DIM * HID,
                   DIM, HID, y * 32, x * 32, t);
  } else {
    int bb = b - NBS - ZPB - TW1B;     // z*256 + y*16 + x ; R=HID, Cc=HID
    int z = bb >> 8, r = bb & 255, y = r >> 4, x = r & 15;
    transpose_body(W2 + (size_t)z * HID * HID, w2t + (size_t)z * HID * HID,
                   HID, HID, y * 32, x * 32, t);
  }
}

// per-cluster scan over blocks -> blkbase, cnt, offs
__global__ void prefix_kernel(const int* __restrict__ blkcnt, int* __restrict__ blkbase,
                              int* __restrict__ cnt, int* __restrict__ offs) {
  int c = threadIdx.x;
  if (c < NCLUS) {
    int run = 0;
    for (int b = 0; b < NBS; ++b) {
      blkbase[b * NCLUS + c] = run;
      run += blkcnt[b * NCLUS + c];
    }
    cnt[c] = run;
  }
  __syncthreads();
  if (c == 0) {
    int a = 0;
    for (int i = 0; i < NCLUS; ++i) { offs[i] = a; a += cnt[i]; }
    offs[NCLUS] = a;
  }
}

// order[offs[c] + blkbase + waveprefix + rank_in_wave] = n
__global__ __launch_bounds__(256) void scatter2_kernel(
    const int* __restrict__ cid, const int* __restrict__ blkbase,
    const int* __restrict__ offs, int* __restrict__ order) {
  __shared__ int wcnt[4][16];
  __shared__ int wbase[4][16];
  int tid = threadIdx.x;
  int lane = tid & 63, w = tid >> 6;
  int n = blockIdx.x * 256 + tid;
  int mycid = (n < NT) ? cid[n] : -1;
  unsigned long long lmask = (lane == 63) ? ~0ull >> 1 : (1ull << lane) - 1;
  int myrank = 0;
#pragma unroll
  for (int c = 0; c < NCLUS; ++c) {
    unsigned long long m = __ballot(mycid == c);
    if (mycid == c) myrank = __popcll(m & lmask);
    if (lane == c) wcnt[w][c] = __popcll(m);
  }
  __syncthreads();
  if (tid < NCLUS) {
    int pre = blkbase[blockIdx.x * NCLUS + tid];
#pragma unroll
    for (int ww = 0; ww < 4; ++ww) { wbase[ww][tid] = pre; pre += wcnt[ww][tid]; }
  }
  __syncthreads();
  if (n < NT) order[offs[mycid] + wbase[w][mycid] + myrank] = n;
}

// xs[i][:] = bf16(x[order[i]][:])  -- sorted, casted copy of x
__global__ void gather_cast(const float* __restrict__ x, const int* __restrict__ order,
                            bf16* __restrict__ xs) {
  int t = blockIdx.x * 256 + threadIdx.x;  // one thread per 8 elements
  int row = t >> 7;                        // 128 threads per row (1024 elems)
  if (row >= NT) return;
  int col = (t & 127) << 3;
  const f32x4* p = (const f32x4*)(x + (size_t)order[row] * DIM + col);
  f32x4 u = p[0], v = p[1];
  bf16x8 w;
  w[0] = (bf16)u[0]; w[1] = (bf16)u[1]; w[2] = (bf16)u[2]; w[3] = (bf16)u[3];
  w[4] = (bf16)v[0]; w[5] = (bf16)v[1]; w[6] = (bf16)v[2]; w[7] = (bf16)v[3];
  *(bf16x8*)(xs + (size_t)row * DIM + col) = w;
}

// XCD-grouping decode: the 4 n-blocks of one (cluster,row-tile) group get
// dispatch slots congruent mod 8 -> same XCD L2 serves the shared A panel.
__device__ __forceinline__ bool decode_grp2(int d, int& c, int& rt, int& j) {
  int x8 = d & 7, s = d >> 3;
  int g = (s >> 2) * 8 + x8;
  if (g >= NRT2 * NCLUS) return false;
  j = s & 3;
  c = g / NRT2;
  rt = g - c * NRT2;
  return true;
}

// ---------------- GEMM1: h1 = relu(xs @ W1[c]^T + b1[c]) ----------------
// 64x128 tile, BK=64, 2 waves (wave w owns rows w*32..w*32+31, all 128 cols).

__global__ __launch_bounds__(128, 3) void gemm1_kernel(
    const bf16* __restrict__ xs, const bf16* __restrict__ w1t, const float* __restrict__ b1,
    const int* __restrict__ offs, const int* __restrict__ cnt, bf16* __restrict__ h1) {
  int c, rt, j;
  if (!decode_grp2(blockIdx.x, c, rt, j)) return;
  int cntc = cnt[c];
  int row0 = rt * 64;
  if (row0 >= cntc) return;
  int seg = offs[c];
  int n0 = j * 128;

  __shared__ bf16 Als[64 * 64];   // [row][k]
  __shared__ bf16 Bls[128 * 64];  // [n][k]

  int tid = threadIdx.x;
  int lane = tid & 63, w = tid >> 6;

  const bf16* aptr[4]; int aoff[4];
  const bf16* bptr[8]; int boff[8];
#pragma unroll
  for (int i = 0; i < 4; ++i) {             // A: 8 chunks of 8 rows x 64 k
    int ch = i * 2 + w;
    int r = ch * 8 + (lane >> 3);
    int kk = (lane & 7) << 3;
    int ar = seg + row0 + r; if (ar > NT - 1) ar = NT - 1;
    aptr[i] = xs + (size_t)ar * DIM + kk;
    aoff[i] = ch * 512;
  }
#pragma unroll
  for (int i = 0; i < 8; ++i) {             // B: 16 chunks
    int ch = i * 2 + w;
    int r = ch * 8 + (lane >> 3);
    int kk = (lane & 7) << 3;
    bptr[i] = w1t + (size_t)(c * HID + n0 + r) * DIM + kk;
    boff[i] = ch * 512;
  }

  f32x4 acc[2][8];
#pragma unroll
  for (int m = 0; m < 2; m++)
#pragma unroll
    for (int n = 0; n < 8; n++) acc[m][n] = {0.f, 0.f, 0.f, 0.f};

  for (int k0 = 0; k0 < DIM; k0 += 64) {
#pragma unroll
    for (int i = 0; i < 4; ++i) gload_lds16(aptr[i] + k0, &Als[aoff[i]]);
#pragma unroll
    for (int i = 0; i < 8; ++i) gload_lds16(bptr[i] + k0, &Bls[boff[i]]);
    __syncthreads();
#pragma unroll
    for (int ks = 0; ks < 2; ++ks) {
      int ko = ks * 32 + ((lane >> 4) << 3);
      bf16x8 a[2], b[8];
#pragma unroll
      for (int m = 0; m < 2; m++)
        a[m] = *(const bf16x8*)(&Als[(w * 32 + m * 16 + (lane & 15)) * 64 + ko]);
#pragma unroll
      for (int n = 0; n < 8; n++)
        b[n] = *(const bf16x8*)(&Bls[(n * 16 + (lane & 15)) * 64 + ko]);
#pragma unroll
      for (int m = 0; m < 2; m++)
#pragma unroll
        for (int n = 0; n < 8; n++)
          acc[m][n] = __builtin_amdgcn_mfma_f32_16x16x32_bf16(a[m], b[n], acc[m][n], 0, 0, 0);
    }
    __syncthreads();
  }

  int valid = cntc - row0; if (valid > 64) valid = 64;
#pragma unroll
  for (int n = 0; n < 8; n++) {
    int col = n0 + n * 16 + (lane & 15);
    float bias = b1[c * HID + col];
#pragma unroll
    for (int m = 0; m < 2; m++) {
      int rbase = w * 32 + m * 16 + ((lane >> 4) << 2);
#pragma unroll
      for (int e = 0; e < 4; e++) {
        int r = rbase + e;
        if (r < valid) {
          float v = acc[m][n][e] + bias;
          h1[(size_t)(seg + row0 + r) * HID + col] = (bf16)(v > 0.f ? v : 0.f);
        }
      }
    }
  }
}

// ---------------- GEMM2: pool[c] += colsum(relu(h1 @ W2[c]^T + b2[c])) ----------------

__global__ __launch_bounds__(128, 3) void gemm2_kernel(
    const bf16* __restrict__ h1, const bf16* __restrict__ w2t, const float* __restrict__ b2,
    const int* __restrict__ offs, const int* __restrict__ cnt, float* __restrict__ pool) {
  int c, rt, j;
  if (!decode_grp2(blockIdx.x, c, rt, j)) return;
  int cntc = cnt[c];
  int row0 = rt * 64;
  if (row0 >= cntc) return;
  int seg = offs[c];
  int n0 = j * 128;
  int valid = cntc - row0; if (valid > 64) valid = 64;

  __shared__ bf16 Als[64 * 64];
  __shared__ bf16 Bls[128 * 64];

  int tid = threadIdx.x;
  int lane = tid & 63, w = tid >> 6;

  const bf16* aptr[4]; int aoff[4];
  const bf16* bptr[8]; int boff[8];
#pragma unroll
  for (int i = 0; i < 4; ++i) {
    int ch = i * 2 + w;
    int r = ch * 8 + (lane >> 3);
    int kk = (lane & 7) << 3;
    int ar = seg + row0 + r; if (ar > NT - 1) ar = NT - 1;
    aptr[i] = h1 + (size_t)ar * HID + kk;
    aoff[i] = ch * 512;
  }
#pragma unroll
  for (int i = 0; i < 8; ++i) {
    int ch = i * 2 + w;
    int r = ch * 8 + (lane >> 3);
    int kk = (lane & 7) << 3;
    bptr[i] = w2t + (size_t)(c * HID + n0 + r) * HID + kk;
    boff[i] = ch * 512;
  }

  f32x4 acc[2][8];
#pragma unroll
  for (int m = 0; m < 2; m++)
#pragma unroll
    for (int n = 0; n < 8; n++) acc[m][n] = {0.f, 0.f, 0.f, 0.f};

  for (int k0 = 0; k0 < HID; k0 += 64) {
#pragma unroll
    for (int i = 0; i < 4; ++i) gload_lds16(aptr[i] + k0, &Als[aoff[i]]);
#pragma unroll
    for (int i = 0; i < 8; ++i) gload_lds16(bptr[i] + k0, &Bls[boff[i]]);
    __syncthreads();
#pragma unroll
    for (int ks = 0; ks < 2; ++ks) {
      int ko = ks * 32 + ((lane >> 4) << 3);
      bf16x8 a[2], b[8];
#pragma unroll
      for (int m = 0; m < 2; m++)
        a[m] = *(const bf16x8*)(&Als[(w * 32 + m * 16 + (lane & 15)) * 64 + ko]);
#pragma unroll
      for (int n = 0; n < 8; n++)
        b[n] = *(const bf16x8*)(&Bls[(n * 16 + (lane & 15)) * 64 + ko]);
#pragma unroll
      for (int m = 0; m < 2; m++)
#pragma unroll
        for (int n = 0; n < 8; n++)
          acc[m][n] = __builtin_amdgcn_mfma_f32_16x16x32_bf16(a[m], b[n], acc[m][n], 0, 0, 0);
    }
    __syncthreads();
  }

  // bias + relu + masked column-sum into pool
#pragma unroll
  for (int n = 0; n < 8; n++) {
    int col = n0 + n * 16 + (lane & 15);
    float bias = b2[c * HID + col];
    float s = 0.f;
#pragma unroll
    for (int m = 0; m < 2; m++) {
      int rbase = w * 32 + m * 16 + ((lane >> 4) << 2);
#pragma unroll
      for (int e = 0; e < 4; e++) {
        if (rbase + e < valid) {
          float v = acc[m][n][e] + bias;
          s += (v > 0.f ? v : 0.f);
        }
      }
    }
    s += __shfl_xor(s, 16);
    s += __shfl_xor(s, 32);
    if (lane < 16) atomicAdd(&pool[c * HID + col], s);
  }
}

// ---------------- tails (fp32, parallelized) ----------------

__global__ __launch_bounds__(256) void tail_fc(
    const float* __restrict__ pool, const int* __restrict__ cnt,
    const float* __restrict__ fcW, const float* __restrict__ fcb,
    float* __restrict__ hbuf) {
  int c = blockIdx.x >> 3;
  int jt = blockIdx.x & 7;
  __shared__ float hc[HID];
  __shared__ float red[4][64];
  int tid = threadIdx.x;
  float inv = 1.f / fmaxf((float)cnt[c], 1.f);
  for (int k = tid; k < HID; k += 256) hc[k] = pool[c * HID + k] * inv;
  __syncthreads();
  int jl = tid & 63, kg = tid >> 6;
  int j = jt * 64 + jl;
  float s = 0.f;
#pragma unroll 4
  for (int k = kg * 128; k < kg * 128 + 128; ++k) s += hc[k] * fcW[(size_t)k * HID + j];
  red[kg][jl] = s;
  __syncthreads();
  if (kg == 0) {
    float v = red[0][jl] + red[1][jl] + red[2][jl] + red[3][jl] + fcb[j];
    hbuf[c * HID + j] = fmaxf(v, 0.f);
  }
}

__global__ __launch_bounds__(1024) void tail_att(
    const float* __restrict__ hbuf,
    const float* __restrict__ Wa, const float* __restrict__ ba,
    const float* __restrict__ Wb, const float* __restrict__ bb,
    const float* __restrict__ Wc, const float* __restrict__ bc,
    float* __restrict__ score) {
  int c = blockIdx.x;
  __shared__ float h[HID];
  __shared__ float ra[4][DATT_N];
  __shared__ float rb[4][DATT_N];
  __shared__ float sc[DATT_N];
  int tid = threadIdx.x;
  for (int k = tid; k < HID; k += 1024) h[k] = hbuf[c * HID + k];
  __syncthreads();
  int jl = tid & 255, kg = tid >> 8;
  float sa = 0.f, sb = 0.f;
#pragma unroll 4
  for (int k = kg * 128; k < kg * 128 + 128; ++k) {
    float hv = h[k];
    sa += hv * Wa[(size_t)k * DATT_N + jl];
    sb += hv * Wb[(size_t)k * DATT_N + jl];
  }
  ra[kg][jl] = sa;
  rb[kg][jl] = sb;
  __syncthreads();
  if (kg == 0) {
    float va = ra[0][jl] + ra[1][jl] + ra[2][jl] + ra[3][jl] + ba[jl];
    float vb = rb[0][jl] + rb[1][jl] + rb[2][jl] + rb[3][jl] + bb[jl];
    float av = tanhf(va);
    float bv = 1.f / (1.f + expf(-vb));
    sc[jl] = av * bv * Wc[jl];
  }
  __syncthreads();
  for (int s2 = 128; s2 > 0; s2 >>= 1) {
    if (tid < s2) sc[tid] += sc[tid + s2];
    __syncthreads();
  }
  if (tid == 0) score[c] = sc[0] + bc[0];
}

__global__ __launch_bounds__(1024) void tail_fin(
    const float* __restrict__ score, const float* __restrict__ hbuf,
    const float* __restrict__ rhoW, const float* __restrict__ rhob,
    const float* __restrict__ clsW, const float* __restrict__ clsb,
    float* __restrict__ out) {
  __shared__ float Asm[NCLUS];
  __shared__ float hp[HID];
  __shared__ float rr[4][DATT_N];
  __shared__ float hr[DATT_N];
  __shared__ float lg[NCLS_N];
  int tid = threadIdx.x;
  if (tid == 0) {
    float mx = -1e30f;
    for (int c = 0; c < NCLUS; c++) mx = fmaxf(mx, score[c]);
    float sum = 0.f, e[NCLUS];
    for (int c = 0; c < NCLUS; c++) { e[c] = expf(score[c] - mx); sum += e[c]; }
    for (int c = 0; c < NCLUS; c++) Asm[c] = e[c] / sum;
  }
  __syncthreads();
  if (tid < HID) {
    float s = 0.f;
#pragma unroll
    for (int c = 0; c < NCLUS; c++) s += Asm[c] * hbuf[c * HID + tid];
    hp[tid] = s;
  }
  __syncthreads();
  int jl = tid & 255, kg = tid >> 8;
  float s = 0.f;
#pragma unroll 4
  for (int k = kg * 128; k < kg * 128 + 128; ++k) s += hp[k] * rhoW[(size_t)k * DATT_N + jl];
  rr[kg][jl] = s;
  __syncthreads();
  if (kg == 0) hr[jl] = fmaxf(rr[0][jl] + rr[1][jl] + rr[2][jl] + rr[3][jl] + rhob[jl], 0.f);
  __syncthreads();
  if (tid < NCLS_N * 64) {
    int t = tid >> 6, l = tid & 63;
    float cs = 0.f;
    for (int j = l; j < DATT_N; j += 64) cs += hr[j] * clsW[j * NCLS_N + t];
#pragma unroll
    for (int w = 32; w > 0; w >>= 1) cs += __shfl_xor(cs, w);
    if (l == 0) lg[t] = cs + clsb[t];
  }
  __syncthreads();
  if (tid == 0) {
    float mx = lg[0];
    int am = 0;
    for (int t = 1; t < NCLS_N; t++) if (lg[t] > mx) { mx = lg[t]; am = t; }
    float sum = 0.f, e[NCLS_N];
    for (int t = 0; t < NCLS_N; t++) { e[t] = expf(lg[t] - mx); sum += e[t]; }
    for (int t = 0; t < NCLS_N; t++) {
      out[t] = lg[t];
      out[NCLS_N + t] = e[t] / sum;
    }
    out[2 * NCLS_N] = (float)am;
  }
}

// ---------------- launch ----------------

extern "C" void kernel_launch(void* const* d_in, const int* in_sizes, int n_in,
                              void* d_out, int out_size, void* d_ws, size_t ws_size,
                              hipStream_t stream) {
  const float* x    = (const float*)d_in[0];
  const int*   cid  = (const int*)d_in[1];
  const float* W1   = (const float*)d_in[2];
  const float* b1   = (const float*)d_in[3];
  const float* W2   = (const float*)d_in[4];
  const float* b2   = (const float*)d_in[5];
  const float* fcW  = (const float*)d_in[6];
  const float* fcb  = (const float*)d_in[7];
  const float* Wa   = (const float*)d_in[8];
  const float* ba   = (const float*)d_in[9];
  const float* Wb   = (const float*)d_in[10];
  const float* bb   = (const float*)d_in[11];
  const float* Wc   = (const float*)d_in[12];
  const float* bc   = (const float*)d_in[13];
  const float* rhoW = (const float*)d_in[14];
  const float* rhob = (const float*)d_in[15];
  const float* clsW = (const float*)d_in[16];
  const float* clsb = (const float*)d_in[17];
  float* out = (float*)d_out;

  char* ws = (char*)d_ws;
  int*   cnt     = (int*)(ws + 0);
  int*   offs    = (int*)(ws + 64);
  float* score   = (float*)(ws + 128);
  int*   blkcnt  = (int*)(ws + 256);                    // NBS*NCLUS = 790 ints
  int*   blkbase = (int*)(ws + 256 + 4096);
  int*   order   = (int*)(ws + 256 + 8192);             // NT ints
  float* pool    = (float*)(ws + 256 + 8192 + 80000);
  float* hbuf    = (float*)(ws + 256 + 8192 + 80000 + NCLUS * HID * 4);
  size_t o = 256 + 8192 + 80000 + 2ull * NCLUS * HID * 4;
  o = (o + 255) & ~(size_t)255;
  bf16* w1t = (bf16*)(ws + o); o += (size_t)NCLUS * HID * DIM * 2;
  bf16* w2t = (bf16*)(ws + o); o += (size_t)NCLUS * HID * HID * 2;
  bf16* h1  = (bf16*)(ws + o); o += (size_t)NT * HID * 2;
  bf16* xs  = (bf16*)(ws + o); o += (size_t)NT * DIM * 2;

  setup_kernel<<<dim3(NBS + ZPB + TW1B + TW2B), dim3(256), 0, stream>>>(
      cid, blkcnt, pool, W1, w1t, W2, w2t);
  prefix_kernel<<<dim3(1), dim3(64), 0, stream>>>(blkcnt, blkbase, cnt, offs);
  scatter2_kernel<<<dim3(NBS), dim3(256), 0, stream>>>(cid, blkbase, offs, order);
  gather_cast<<<dim3(NT * 128 / 256), dim3(256), 0, stream>>>(x, order, xs);

  int nblk = 8 * ((NRT2 * NCLUS + 7) / 8) * 4;   // 12544
  gemm1_kernel<<<dim3(nblk), dim3(128), 0, stream>>>(xs, w1t, b1, offs, cnt, h1);
  gemm2_kernel<<<dim3(nblk), dim3(128), 0, stream>>>(h1, w2t, b2, offs, cnt, pool);

  tail_fc<<<dim3(NCLUS * 8), dim3(256), 0, stream>>>(pool, cnt, fcW, fcb, hbuf);
  tail_att<<<dim3(NCLUS), dim3(1024), 0, stream>>>(hbuf, Wa, ba, Wb, bb, Wc, bc, score);
  tail_fin<<<dim3(1), dim3(1024), 0, stream>>>(score, hbuf, rhoW, rhob, clsW, clsb, out);
}

// Round 7
// 137.140 us; speedup vs baseline: 1.1908x; 1.0744x over previous
//
#include <hip/hip_runtime.h>
#include <hip/hip_bf16.h>
#include <stdint.h>

#define NT 20000
#define DIM 1024
#define HID 512
#define DATT_N 256
#define NCLUS 10
#define NCLS_N 4
#define NBS 79        // ceil(NT/256) sort blocks
#define NRT2 313      // ceil(NT/64) row tiles

typedef __bf16 bf16;
typedef __attribute__((ext_vector_type(8))) __bf16 bf16x8;
typedef __attribute__((ext_vector_type(4))) float f32x4;

__device__ __forceinline__ void gload_lds16(const void* g, void* l) {
  __builtin_amdgcn_global_load_lds(
      (const __attribute__((address_space(1))) unsigned int*)g,
      (__attribute__((address_space(3))) unsigned int*)l, 16, 0, 0);
}

// ---------------- fused setup: hist + zero_pool + W1/W2 transpose-cast ----------------

__device__ __forceinline__ void transpose_body(const float* __restrict__ s,
                                               bf16* __restrict__ d, int R, int Cc,
                                               int i0, int j0, float (*t)[33]) {
  int tx = threadIdx.x & 31, ty = threadIdx.x >> 5;
#pragma unroll
  for (int yy = 0; yy < 32; yy += 8)
    t[ty + yy][tx] = s[(size_t)(i0 + ty + yy) * Cc + (j0 + tx)];
  __syncthreads();
#pragma unroll
  for (int yy = 0; yy < 32; yy += 8)
    d[(size_t)(j0 + ty + yy) * R + (i0 + tx)] = (bf16)t[tx][ty + yy];
}

#define ZPB ((NCLUS * HID + 255) / 256)     // 20 zero blocks
#define TW1B (16 * 32 * NCLUS)              // 5120 W1-transpose blocks
#define TW2B (16 * 16 * NCLUS)              // 2560 W2-transpose blocks

__global__ __launch_bounds__(256) void setup_kernel(
    const int* __restrict__ cid, int* __restrict__ blkcnt, float* __restrict__ pool,
    const float* __restrict__ W1, bf16* __restrict__ w1t,
    const float* __restrict__ W2, bf16* __restrict__ w2t) {
  __shared__ float t[32][33];
  __shared__ int wcnt[4][16];
  int b = blockIdx.x;
  int tid = threadIdx.x;
  if (b < NBS) {
    // per-block cluster histogram via wave ballots
    int lane = tid & 63, w = tid >> 6;
    int n = b * 256 + tid;
    int mycid = (n < NT) ? cid[n] : -1;
#pragma unroll
    for (int c = 0; c < NCLUS; ++c) {
      unsigned long long m = __ballot(mycid == c);
      if (lane == c) wcnt[w][c] = __popcll(m);
    }
    __syncthreads();
    if (tid < NCLUS)
      blkcnt[b * NCLUS + tid] =
          wcnt[0][tid] + wcnt[1][tid] + wcnt[2][tid] + wcnt[3][tid];
  } else if (b < NBS + ZPB) {
    int i = (b - NBS) * 256 + tid;
    if (i < NCLUS * HID) pool[i] = 0.f;
  } else if (b < NBS + ZPB + TW1B) {
    int bb = b - NBS - ZPB;            // z*512 + y*16 + x ; R=DIM, Cc=HID
    int z = bb >> 9, r = bb & 511, y = r >> 4, x = r & 15;
    transpose_body(W1 + (size_t)z * DIM * HID, w1t + (size_t)z * DIM * HID,
                   DIM, HID, y * 32, x * 32, t);
  } else {
    int bb = b - NBS - ZPB - TW1B;     // z*256 + y*16 + x ; R=HID, Cc=HID
    int z = bb >> 8, r = bb & 255, y = r >> 4, x = r & 15;
    transpose_body(W2 + (size_t)z * HID * HID, w2t + (size_t)z * HID * HID,
                   HID, HID, y * 32, x * 32, t);
  }
}

// per-cluster scan over blocks -> blkbase, cnt, offs
__global__ void prefix_kernel(const int* __restrict__ blkcnt, int* __restrict__ blkbase,
                              int* __restrict__ cnt, int* __restrict__ offs) {
  int c = threadIdx.x;
  if (c < NCLUS) {
    int run = 0;
    for (int b = 0; b < NBS; ++b) {
      blkbase[b * NCLUS + c] = run;
      run += blkcnt[b * NCLUS + c];
    }
    cnt[c] = run;
  }
  __syncthreads();
  if (c == 0) {
    int a = 0;
    for (int i = 0; i < NCLUS; ++i) { offs[i] = a; a += cnt[i]; }
    offs[NCLUS] = a;
  }
}

// order[offs[c] + blkbase + waveprefix + rank_in_wave] = n
__global__ __launch_bounds__(256) void scatter2_kernel(
    const int* __restrict__ cid, const int* __restrict__ blkbase,
    const int* __restrict__ offs, int* __restrict__ order) {
  __shared__ int wcnt[4][16];
  __shared__ int wbase[4][16];
  int tid = threadIdx.x;
  int lane = tid & 63, w = tid >> 6;
  int n = blockIdx.x * 256 + tid;
  int mycid = (n < NT) ? cid[n] : -1;
  unsigned long long lmask = (lane == 63) ? ~0ull >> 1 : (1ull << lane) - 1;
  int myrank = 0;
#pragma unroll
  for (int c = 0; c < NCLUS; ++c) {
    unsigned long long m = __ballot(mycid == c);
    if (mycid == c) myrank = __popcll(m & lmask);
    if (lane == c) wcnt[w][c] = __popcll(m);
  }
  __syncthreads();
  if (tid < NCLUS) {
    int pre = blkbase[blockIdx.x * NCLUS + tid];
#pragma unroll
    for (int ww = 0; ww < 4; ++ww) { wbase[ww][tid] = pre; pre += wcnt[ww][tid]; }
  }
  __syncthreads();
  if (n < NT) order[offs[mycid] + wbase[w][mycid] + myrank] = n;
}

// xs[i][:] = bf16(x[order[i]][:])  -- sorted, casted copy of x
__global__ void gather_cast(const float* __restrict__ x, const int* __restrict__ order,
                            bf16* __restrict__ xs) {
  int t = blockIdx.x * 256 + threadIdx.x;  // one thread per 8 elements
  int row = t >> 7;                        // 128 threads per row (1024 elems)
  if (row >= NT) return;
  int col = (t & 127) << 3;
  const f32x4* p = (const f32x4*)(x + (size_t)order[row] * DIM + col);
  f32x4 u = p[0], v = p[1];
  bf16x8 w;
  w[0] = (bf16)u[0]; w[1] = (bf16)u[1]; w[2] = (bf16)u[2]; w[3] = (bf16)u[3];
  w[4] = (bf16)v[0]; w[5] = (bf16)v[1]; w[6] = (bf16)v[2]; w[7] = (bf16)v[3];
  *(bf16x8*)(xs + (size_t)row * DIM + col) = w;
}

// XCD-grouping decode: the 4 n-blocks of one (cluster,row-tile) group get
// dispatch slots congruent mod 8 -> same XCD L2 serves the shared A panel.
__device__ __forceinline__ bool decode_grp2(int d, int& c, int& rt, int& j) {
  int x8 = d & 7, s = d >> 3;
  int g = (s >> 2) * 8 + x8;
  if (g >= NRT2 * NCLUS) return false;
  j = s & 3;
  c = g / NRT2;
  rt = g - c * NRT2;
  return true;
}

// ---------------- GEMM1: h1 = relu(xs @ W1[c]^T + b1[c]) ----------------
// 64x128 tile, BK=64, 2 waves. T2 both-sides XOR swizzle (rule 21):
// LDS dest stays linear (gload_lds), SOURCE column is pre-swizzled so LDS
// slot s of row r holds global 16B-slot s^(r&7); fragment reads XOR the
// same pattern -> bank-balanced ds_read_b128.

__global__ __launch_bounds__(128, 3) void gemm1_kernel(
    const bf16* __restrict__ xs, const bf16* __restrict__ w1t, const float* __restrict__ b1,
    const int* __restrict__ offs, const int* __restrict__ cnt, bf16* __restrict__ h1) {
  int c, rt, j;
  if (!decode_grp2(blockIdx.x, c, rt, j)) return;
  int cntc = cnt[c];
  int row0 = rt * 64;
  if (row0 >= cntc) return;
  int seg = offs[c];
  int n0 = j * 128;

  __shared__ bf16 Als[64 * 64];   // [row][k] (k pre-swizzled per row)
  __shared__ bf16 Bls[128 * 64];  // [n][k]

  int tid = threadIdx.x;
  int lane = tid & 63, w = tid >> 6;
  int rx = lane & 7, hi = lane >> 4;

  // source-swizzled column: lane fetches global slot (lane&7)^(lane>>3)
  int kswz = ((lane & 7) ^ (lane >> 3)) << 3;

  const bf16* aptr[4]; int aoff[4];
  const bf16* bptr[8]; int boff[8];
#pragma unroll
  for (int i = 0; i < 4; ++i) {             // A: 8 chunks of 8 rows x 64 k
    int ch = i * 2 + w;
    int r = ch * 8 + (lane >> 3);
    int ar = seg + row0 + r; if (ar > NT - 1) ar = NT - 1;
    aptr[i] = xs + (size_t)ar * DIM + kswz;
    aoff[i] = ch * 512;
  }
#pragma unroll
  for (int i = 0; i < 8; ++i) {             // B: 16 chunks
    int ch = i * 2 + w;
    int r = ch * 8 + (lane >> 3);
    bptr[i] = w1t + (size_t)(c * HID + n0 + r) * DIM + kswz;
    boff[i] = ch * 512;
  }

  f32x4 acc[2][8];
#pragma unroll
  for (int m = 0; m < 2; m++)
#pragma unroll
    for (int n = 0; n < 8; n++) acc[m][n] = {0.f, 0.f, 0.f, 0.f};

  for (int k0 = 0; k0 < DIM; k0 += 64) {
#pragma unroll
    for (int i = 0; i < 4; ++i) gload_lds16(aptr[i] + k0, &Als[aoff[i]]);
#pragma unroll
    for (int i = 0; i < 8; ++i) gload_lds16(bptr[i] + k0, &Bls[boff[i]]);
    __syncthreads();
#pragma unroll
    for (int ks = 0; ks < 2; ++ks) {
      int t16 = ks * 4 + hi;                // true 16B-slot index
      int ko = ((t16 ^ rx) << 3);           // swizzled read slot
      bf16x8 a[2], b[8];
#pragma unroll
      for (int m = 0; m < 2; m++)
        a[m] = *(const bf16x8*)(&Als[(w * 32 + m * 16 + (lane & 15)) * 64 + ko]);
#pragma unroll
      for (int n = 0; n < 8; n++)
        b[n] = *(const bf16x8*)(&Bls[(n * 16 + (lane & 15)) * 64 + ko]);
#pragma unroll
      for (int m = 0; m < 2; m++)
#pragma unroll
        for (int n = 0; n < 8; n++)
          acc[m][n] = __builtin_amdgcn_mfma_f32_16x16x32_bf16(a[m], b[n], acc[m][n], 0, 0, 0);
    }
    __syncthreads();
  }

  int valid = cntc - row0; if (valid > 64) valid = 64;
#pragma unroll
  for (int n = 0; n < 8; n++) {
    int col = n0 + n * 16 + (lane & 15);
    float bias = b1[c * HID + col];
#pragma unroll
    for (int m = 0; m < 2; m++) {
      int rbase = w * 32 + m * 16 + ((lane >> 4) << 2);
#pragma unroll
      for (int e = 0; e < 4; e++) {
        int r = rbase + e;
        if (r < valid) {
          float v = acc[m][n][e] + bias;
          h1[(size_t)(seg + row0 + r) * HID + col] = (bf16)(v > 0.f ? v : 0.f);
        }
      }
    }
  }
}

// ---------------- GEMM2: pool[c] += colsum(relu(h1 @ W2[c]^T + b2[c])) ----------------

__global__ __launch_bounds__(128, 3) void gemm2_kernel(
    const bf16* __restrict__ h1, const bf16* __restrict__ w2t, const float* __restrict__ b2,
    const int* __restrict__ offs, const int* __restrict__ cnt, float* __restrict__ pool) {
  int c, rt, j;
  if (!decode_grp2(blockIdx.x, c, rt, j)) return;
  int cntc = cnt[c];
  int row0 = rt * 64;
  if (row0 >= cntc) return;
  int seg = offs[c];
  int n0 = j * 128;
  int valid = cntc - row0; if (valid > 64) valid = 64;

  __shared__ bf16 Als[64 * 64];
  __shared__ bf16 Bls[128 * 64];

  int tid = threadIdx.x;
  int lane = tid & 63, w = tid >> 6;
  int rx = lane & 7, hi = lane >> 4;
  int kswz = ((lane & 7) ^ (lane >> 3)) << 3;

  const bf16* aptr[4]; int aoff[4];
  const bf16* bptr[8]; int boff[8];
#pragma unroll
  for (int i = 0; i < 4; ++i) {
    int ch = i * 2 + w;
    int r = ch * 8 + (lane >> 3);
    int ar = seg + row0 + r; if (ar > NT - 1) ar = NT - 1;
    aptr[i] = h1 + (size_t)ar * HID + kswz;
    aoff[i] = ch * 512;
  }
#pragma unroll
  for (int i = 0; i < 8; ++i) {
    int ch = i * 2 + w;
    int r = ch * 8 + (lane >> 3);
    bptr[i] = w2t + (size_t)(c * HID + n0 + r) * HID + kswz;
    boff[i] = ch * 512;
  }

  f32x4 acc[2][8];
#pragma unroll
  for (int m = 0; m < 2; m++)
#pragma unroll
    for (int n = 0; n < 8; n++) acc[m][n] = {0.f, 0.f, 0.f, 0.f};

  for (int k0 = 0; k0 < HID; k0 += 64) {
#pragma unroll
    for (int i = 0; i < 4; ++i) gload_lds16(aptr[i] + k0, &Als[aoff[i]]);
#pragma unroll
    for (int i = 0; i < 8; ++i) gload_lds16(bptr[i] + k0, &Bls[boff[i]]);
    __syncthreads();
#pragma unroll
    for (int ks = 0; ks < 2; ++ks) {
      int t16 = ks * 4 + hi;
      int ko = ((t16 ^ rx) << 3);
      bf16x8 a[2], b[8];
#pragma unroll
      for (int m = 0; m < 2; m++)
        a[m] = *(const bf16x8*)(&Als[(w * 32 + m * 16 + (lane & 15)) * 64 + ko]);
#pragma unroll
      for (int n = 0; n < 8; n++)
        b[n] = *(const bf16x8*)(&Bls[(n * 16 + (lane & 15)) * 64 + ko]);
#pragma unroll
      for (int m = 0; m < 2; m++)
#pragma unroll
        for (int n = 0; n < 8; n++)
          acc[m][n] = __builtin_amdgcn_mfma_f32_16x16x32_bf16(a[m], b[n], acc[m][n], 0, 0, 0);
    }
    __syncthreads();
  }

  // bias + relu + masked column-sum into pool
#pragma unroll
  for (int n = 0; n < 8; n++) {
    int col = n0 + n * 16 + (lane & 15);
    float bias = b2[c * HID + col];
    float s = 0.f;
#pragma unroll
    for (int m = 0; m < 2; m++) {
      int rbase = w * 32 + m * 16 + ((lane >> 4) << 2);
#pragma unroll
      for (int e = 0; e < 4; e++) {
        if (rbase + e < valid) {
          float v = acc[m][n][e] + bias;
          s += (v > 0.f ? v : 0.f);
        }
      }
    }
    s += __shfl_xor(s, 16);
    s += __shfl_xor(s, 32);
    if (lane < 16) atomicAdd(&pool[c * HID + col], s);
  }
}

// ---------------- tails (fp32, parallelized) ----------------

__global__ __launch_bounds__(256) void tail_fc(
    const float* __restrict__ pool, const int* __restrict__ cnt,
    const float* __restrict__ fcW, const float* __restrict__ fcb,
    float* __restrict__ hbuf) {
  int c = blockIdx.x >> 3;
  int jt = blockIdx.x & 7;
  __shared__ float hc[HID];
  __shared__ float red[4][64];
  int tid = threadIdx.x;
  float inv = 1.f / fmaxf((float)cnt[c], 1.f);
  for (int k = tid; k < HID; k += 256) hc[k] = pool[c * HID + k] * inv;
  __syncthreads();
  int jl = tid & 63, kg = tid >> 6;
  int j = jt * 64 + jl;
  float s = 0.f;
#pragma unroll 4
  for (int k = kg * 128; k < kg * 128 + 128; ++k) s += hc[k] * fcW[(size_t)k * HID + j];
  red[kg][jl] = s;
  __syncthreads();
  if (kg == 0) {
    float v = red[0][jl] + red[1][jl] + red[2][jl] + red[3][jl] + fcb[j];
    hbuf[c * HID + j] = fmaxf(v, 0.f);
  }
}

__global__ __launch_bounds__(1024) void tail_att(
    const float* __restrict__ hbuf,
    const float* __restrict__ Wa, const float* __restrict__ ba,
    const float* __restrict__ Wb, const float* __restrict__ bb,
    const float* __restrict__ Wc, const float* __restrict__ bc,
    float* __restrict__ score) {
  int c = blockIdx.x;
  __shared__ float h[HID];
  __shared__ float ra[4][DATT_N];
  __shared__ float rb[4][DATT_N];
  __shared__ float sc[DATT_N];
  int tid = threadIdx.x;
  for (int k = tid; k < HID; k += 1024) h[k] = hbuf[c * HID + k];
  __syncthreads();
  int jl = tid & 255, kg = tid >> 8;
  float sa = 0.f, sb = 0.f;
#pragma unroll 4
  for (int k = kg * 128; k < kg * 128 + 128; ++k) {
    float hv = h[k];
    sa += hv * Wa[(size_t)k * DATT_N + jl];
    sb += hv * Wb[(size_t)k * DATT_N + jl];
  }
  ra[kg][jl] = sa;
  rb[kg][jl] = sb;
  __syncthreads();
  if (kg == 0) {
    float va = ra[0][jl] + ra[1][jl] + ra[2][jl] + ra[3][jl] + ba[jl];
    float vb = rb[0][jl] + rb[1][jl] + rb[2][jl] + rb[3][jl] + bb[jl];
    float av = tanhf(va);
    float bv = 1.f / (1.f + expf(-vb));
    sc[jl] = av * bv * Wc[jl];
  }
  __syncthreads();
  for (int s2 = 128; s2 > 0; s2 >>= 1) {
    if (tid < s2) sc[tid] += sc[tid + s2];
    __syncthreads();
  }
  if (tid == 0) score[c] = sc[0] + bc[0];
}

__global__ __launch_bounds__(1024) void tail_fin(
    const float* __restrict__ score, const float* __restrict__ hbuf,
    const float* __restrict__ rhoW, const float* __restrict__ rhob,
    const float* __restrict__ clsW, const float* __restrict__ clsb,
    float* __restrict__ out) {
  __shared__ float Asm[NCLUS];
  __shared__ float hp[HID];
  __shared__ float rr[4][DATT_N];
  __shared__ float hr[DATT_N];
  __shared__ float lg[NCLS_N];
  int tid = threadIdx.x;
  if (tid == 0) {
    float mx = -1e30f;
    for (int c = 0; c < NCLUS; c++) mx = fmaxf(mx, score[c]);
    float sum = 0.f, e[NCLUS];
    for (int c = 0; c < NCLUS; c++) { e[c] = expf(score[c] - mx); sum += e[c]; }
    for (int c = 0; c < NCLUS; c++) Asm[c] = e[c] / sum;
  }
  __syncthreads();
  if (tid < HID) {
    float s = 0.f;
#pragma unroll
    for (int c = 0; c < NCLUS; c++) s += Asm[c] * hbuf[c * HID + tid];
    hp[tid] = s;
  }
  __syncthreads();
  int jl = tid & 255, kg = tid >> 8;
  float s = 0.f;
#pragma unroll 4
  for (int k = kg * 128; k < kg * 128 + 128; ++k) s += hp[k] * rhoW[(size_t)k * DATT_N + jl];
  rr[kg][jl] = s;
  __syncthreads();
  if (kg == 0) hr[jl] = fmaxf(rr[0][jl] + rr[1][jl] + rr[2][jl] + rr[3][jl] + rhob[jl], 0.f);
  __syncthreads();
  if (tid < NCLS_N * 64) {
    int t = tid >> 6, l = tid & 63;
    float cs = 0.f;
    for (int j = l; j < DATT_N; j += 64) cs += hr[j] * clsW[j * NCLS_N + t];
#pragma unroll
    for (int w = 32; w > 0; w >>= 1) cs += __shfl_xor(cs, w);
    if (l == 0) lg[t] = cs + clsb[t];
  }
  __syncthreads();
  if (tid == 0) {
    float mx = lg[0];
    int am = 0;
    for (int t = 1; t < NCLS_N; t++) if (lg[t] > mx) { mx = lg[t]; am = t; }
    float sum = 0.f, e[NCLS_N];
    for (int t = 0; t < NCLS_N; t++) { e[t] = expf(lg[t] - mx); sum += e[t]; }
    for (int t = 0; t < NCLS_N; t++) {
      out[t] = lg[t];
      out[NCLS_N + t] = e[t] / sum;
    }
    out[2 * NCLS_N] = (float)am;
  }
}

// ---------------- launch ----------------

extern "C" void kernel_launch(void* const* d_in, const int* in_sizes, int n_in,
                              void* d_out, int out_size, void* d_ws, size_t ws_size,
                              hipStream_t stream) {
  const float* x    = (const float*)d_in[0];
  const int*   cid  = (const int*)d_in[1];
  const float* W1   = (const float*)d_in[2];
  const float* b1   = (const float*)d_in[3];
  const float* W2   = (const float*)d_in[4];
  const float* b2   = (const float*)d_in[5];
  const float* fcW  = (const float*)d_in[6];
  const float* fcb  = (const float*)d_in[7];
  const float* Wa   = (const float*)d_in[8];
  const float* ba   = (const float*)d_in[9];
  const float* Wb   = (const float*)d_in[10];
  const float* bb   = (const float*)d_in[11];
  const float* Wc   = (const float*)d_in[12];
  const float* bc   = (const float*)d_in[13];
  const float* rhoW = (const float*)d_in[14];
  const float* rhob = (const float*)d_in[15];
  const float* clsW = (const float*)d_in[16];
  const float* clsb = (const float*)d_in[17];
  float* out = (float*)d_out;

  char* ws = (char*)d_ws;
  int*   cnt     = (int*)(ws + 0);
  int*   offs    = (int*)(ws + 64);
  float* score   = (float*)(ws + 128);
  int*   blkcnt  = (int*)(ws + 256);                    // NBS*NCLUS = 790 ints
  int*   blkbase = (int*)(ws + 256 + 4096);
  int*   order   = (int*)(ws + 256 + 8192);             // NT ints
  float* pool    = (float*)(ws + 256 + 8192 + 80000);
  float* hbuf    = (float*)(ws + 256 + 8192 + 80000 + NCLUS * HID * 4);
  size_t o = 256 + 8192 + 80000 + 2ull * NCLUS * HID * 4;
  o = (o + 255) & ~(size_t)255;
  bf16* w1t = (bf16*)(ws + o); o += (size_t)NCLUS * HID * DIM * 2;
  bf16* w2t = (bf16*)(ws + o); o += (size_t)NCLUS * HID * HID * 2;
  bf16* h1  = (bf16*)(ws + o); o += (size_t)NT * HID * 2;
  bf16* xs  = (bf16*)(ws + o); o += (size_t)NT * DIM * 2;

  setup_kernel<<<dim3(NBS + ZPB + TW1B + TW2B), dim3(256), 0, stream>>>(
      cid, blkcnt, pool, W1, w1t, W2, w2t);
  prefix_kernel<<<dim3(1), dim3(64), 0, stream>>>(blkcnt, blkbase, cnt, offs);
  scatter2_kernel<<<dim3(NBS), dim3(256), 0, stream>>>(cid, blkbase, offs, order);
  gather_cast<<<dim3(NT * 128 / 256), dim3(256), 0, stream>>>(x, order, xs);

  int nblk = 8 * ((NRT2 * NCLUS + 7) / 8) * 4;   // 12544
  gemm1_kernel<<<dim3(nblk), dim3(128), 0, stream>>>(xs, w1t, b1, offs, cnt, h1);
  gemm2_kernel<<<dim3(nblk), dim3(128), 0, stream>>>(h1, w2t, b2, offs, cnt, pool);

  tail_fc<<<dim3(NCLUS * 8), dim3(256), 0, stream>>>(pool, cnt, fcW, fcb, hbuf);
  tail_att<<<dim3(NCLUS), dim3(1024), 0, stream>>>(hbuf, Wa, ba, Wb, bb, Wc, bc, score);
  tail_fin<<<dim3(1), dim3(1024), 0, stream>>>(score, hbuf, rhoW, rhob, clsW, clsb, out);
}